// Round 1
// 883.319 us; speedup vs baseline: 1.2691x; 1.2691x over previous
//
#include <hip/hip_runtime.h>

// AttentionDecoder: embed -> LSTM(64 steps) -> dot attention -> vocab projection
// B=32 TD=TE=64 V=32000 D=H=512.
// I/O dtypes: ALL float tensors fp32 (per reference); xs int32. Outputs fp32.
// Internally: convert to bf16 at staging (RNE), MFMA 16x16x32_bf16, fp32 accum.
//
// d_out layout (fp32 elems): logits[32][64][32000] | hT[32][512] | cT[32][512] | attn[32][64][64]
// ws layout: xpb bf16[2048][2048] | feat bf16[2048][1024] | hbuf bf16[2][32][512] | flags u32[32]

typedef unsigned short u16;
typedef unsigned int u32;
typedef __bf16 bf16x8 __attribute__((ext_vector_type(8)));
typedef float f32x4 __attribute__((ext_vector_type(4)));
typedef u32 u32x4 __attribute__((ext_vector_type(4)));

__device__ __forceinline__ float bf2f(u16 u){ u32 x = ((u32)u)<<16; return __builtin_bit_cast(float, x); }
__device__ __forceinline__ u16 f2bf(float f){ u32 x = __builtin_bit_cast(u32, f); x += 0x7FFFu + ((x>>16)&1u); return (u16)(x>>16); }
__device__ __forceinline__ u32 pk2(float a, float b){ return (u32)f2bf(a) | ((u32)f2bf(b)<<16); }
__device__ __forceinline__ u32x4 pk8(const float* p){
  f32x4 lo = *(const f32x4*)p, hi = *(const f32x4*)(p+4);
  u32x4 r; r[0]=pk2(lo[0],lo[1]); r[1]=pk2(lo[2],lo[3]); r[2]=pk2(hi[0],hi[1]); r[3]=pk2(hi[2],hi[3]);
  return r;
}

__device__ __forceinline__ f32x4 mfma16(u32x4 a, u32x4 b, f32x4 c){
  return __builtin_amdgcn_mfma_f32_16x16x32_bf16(
      __builtin_bit_cast(bf16x8, a), __builtin_bit_cast(bf16x8, b), c, 0, 0, 0);
}

__device__ __forceinline__ void gld16(const void* g, void* l){
  __builtin_amdgcn_global_load_lds(
      (__attribute__((address_space(1))) void*)(void*)g,
      (__attribute__((address_space(3))) void*)l, 16, 0, 0);
}

// Cache-bypass (coherence-point) ops: sc0 sc1 => bypass L1 and per-XCD L2,
// serviced at the die-level coherence point => cross-XCD visible without
// buffer_inv / buffer_wbl2 cache maintenance.
__device__ __forceinline__ void st_cc(u32* p, u32 v){
  asm volatile("global_store_dword %0, %1, off sc0 sc1" :: "v"(p), "v"(v) : "memory");
}
__device__ __forceinline__ u32x4 ld_cc4(const u32* p){
  u32x4 r;
  asm volatile("global_load_dwordx4 %0, %1, off sc0 sc1" : "=v"(r) : "v"(p) : "memory");
  return r;
}

__device__ __forceinline__ float sigm(float x){ x = fminf(fmaxf(x,-30.f),30.f); return 1.f/(1.f+__expf(-x)); }
__device__ __forceinline__ float tanh_ap(float x){ float xc = fminf(fmaxf(x,-15.f),15.f); float e = __expf(-2.f*xc); return (1.f-e)/(1.f+e); }

// ---- init: h0 fp32 -> hbuf[1] bf16; zero the per-WG seq flags ----
__global__ void k_init(const float* __restrict__ h0, u16* __restrict__ hbuf1, u32* __restrict__ flags){
  int i = blockIdx.x*256 + threadIdx.x;
  hbuf1[i] = f2bf(h0[i]);
  if (i < 32) flags[i] = 0u;
}

// ---------------- Kernel 1: xp = embed_W[xs] @ W_ih^T + (b_ih+b_hh), bf16 out ----------------
__global__ __launch_bounds__(256) void k_xp(const int* __restrict__ xs,
    const float* __restrict__ embW, const float* __restrict__ Wih,
    const float* __restrict__ bih, const float* __restrict__ bhh,
    u16* __restrict__ xpb)
{
  __shared__ u16 sm[16384];           // As[128][64] | Bs[128][64] (bf16)
  u16* As = sm; u16* Bs = sm + 8192;
  const int tid = threadIdx.x;
  const int m0 = blockIdx.x*128, n0 = blockIdx.y*128;
  const int wave = tid>>6, lane = tid&63, quad = lane>>4, lr = lane&15;
  const int wm = wave>>1, wn = wave&1;
  const int rbase = tid>>3, cb = (tid&7)*8;   // 8 floats per lane per row-chunk
  int tok[4];
  #pragma unroll
  for (int i=0;i<4;i++) tok[i] = xs[m0 + i*32 + rbase];
  f32x4 acc[4][4];
  #pragma unroll
  for (int i=0;i<4;i++)
    #pragma unroll
    for (int j=0;j<4;j++) acc[i][j] = (f32x4){0.f,0.f,0.f,0.f};

  for (int kb=0; kb<512; kb+=64){
    #pragma unroll
    for (int i=0;i<4;i++)
      *(u32x4*)(As + i*2048 + tid*8) = pk8(embW + (long)tok[i]*512 + kb + cb);
    #pragma unroll
    for (int i=0;i<4;i++)
      *(u32x4*)(Bs + i*2048 + tid*8) = pk8(Wih + (long)(n0 + i*32 + rbase)*512 + kb + cb);
    __syncthreads();
    #pragma unroll
    for (int k0=0;k0<64;k0+=32){
      u32x4 bf[4];
      #pragma unroll
      for (int j=0;j<4;j++) bf[j] = *(const u32x4*)(Bs + (wn*64 + j*16 + lr)*64 + k0 + quad*8);
      #pragma unroll
      for (int i=0;i<4;i++){
        u32x4 af = *(const u32x4*)(As + (wm*64 + i*16 + lr)*64 + k0 + quad*8);
        #pragma unroll
        for (int j=0;j<4;j++) acc[i][j] = mfma16(af, bf[j], acc[i][j]);
      }
    }
    __syncthreads();
  }
  float bias[4];
  #pragma unroll
  for (int j=0;j<4;j++){ int col = n0 + wn*64 + j*16 + lr; bias[j] = bih[col] + bhh[col]; }
  #pragma unroll
  for (int i=0;i<4;i++)
    #pragma unroll
    for (int j=0;j<4;j++){
      int row = m0 + wm*64 + i*16 + quad*4;
      int col = n0 + wn*64 + j*16 + lr;
      #pragma unroll
      for (int r=0;r<4;r++) xpb[(long)(row+r)*2048 + col] = f2bf(acc[i][j][r] + bias[j]);
    }
}

// ---------------- Kernel 2: persistent LSTM, 32 WGs ----------------
// WG w owns h-cols [w*16, w*16+16); wave q computes gate q; W_hh frags register-resident.
// h exchange: sc0/sc1 cache-bypass stores/loads + per-WG monotonic seq flags.
// NO agent fences (no buffer_inv / buffer_wbl2): release = vmcnt(0)+barrier before
// the flag store; acquire = flag poll + barrier before the data loads. Data and
// flags both live at the coherence point, so visibility is by construction.
__global__ __launch_bounds__(256) void k_lstm(const u16* __restrict__ xpb,
    const float* __restrict__ c0, const float* __restrict__ Whh,
    u16* __restrict__ feat, u16* __restrict__ hbuf, u32* __restrict__ flags,
    float* __restrict__ outH, float* __restrict__ outC)
{
  __shared__ u16 hS[16384];           // h staged [32][512] bf16, XOR-swizzled rows
  __shared__ float gacc[4][32][16];   // gate pre-activations
  const int tid = threadIdx.x, w = blockIdx.x;
  const int wave = tid>>6, lane = tid&63, quad = lane>>4, lr = lane&15;
  const int cbase = w*16;

  u32x4 bfrag[16];                    // W_hh B-fragments (fp32 -> bf16 once)
  const float* wrow = Whh + (long)(wave*512 + cbase + lr)*512;
  #pragma unroll
  for (int kit=0;kit<16;kit++) bfrag[kit] = pk8(wrow + kit*32 + quad*8);

  const int bb0 = tid>>3;             // batch row of this thread's 2 h elems
  const int cc0 = (tid*2)&15;         // even col-pair base within the 16-col slice
  float cst[2];
  cst[0] = c0[bb0*512 + cbase + cc0];
  cst[1] = c0[bb0*512 + cbase + cc0 + 1];

  u32* hb32 = (u32*)hbuf;             // [2][32][256] u32 (2 bf16 per u32)

  // xp gate inputs for current step, packed: xv[q] = {col cc0, col cc0+1}
  u32 xv[4];
  {
    const u16* xp0 = xpb + (long)(bb0*64)*2048 + cbase + cc0;
    #pragma unroll
    for (int q=0;q<4;q++) xv[q] = *(const u32*)(xp0 + q*512);
  }

  for (int t=0;t<64;t++){
    // ---- wait for all WGs to have finished step t-1 (per-WG seq flags) ----
    if (t>0){
      if (wave==0){
        for(;;){
          u32 f = __hip_atomic_load(flags + (lane&31), __ATOMIC_RELAXED, __HIP_MEMORY_SCOPE_AGENT);
          if (__all((int)(f >= (u32)t))) break;
        }
      }
      __syncthreads();
    }
    // ---- gather full h[32][512] from coherence point into swizzled LDS ----
    const u32* src = hb32 + ((t+1)&1)*8192;     // t=0 -> buffer 1 (h0, from k_init)
    u32x4 hreg[8];
    #pragma unroll
    for (int k=0;k<8;k++) hreg[k] = ld_cc4(src + k*1024 + tid*4);
    asm volatile("s_waitcnt vmcnt(0)" ::: "memory");
    __builtin_amdgcn_sched_barrier(0);
    #pragma unroll
    for (int k=0;k<8;k++){
      int row  = k*4 + (tid>>6);                // logical h row (batch)
      int colb = (tid&63)*16;                   // byte col within 1KB row
      *(u32x4*)((char*)hS + row*1024 + (colb ^ ((row&7)<<4))) = hreg[k];
    }
    __syncthreads();

    // ---- gates = h @ W_hh^T (this WG's 16 cols x 4 gates) ----
    f32x4 acc0 = {0.f,0.f,0.f,0.f}, acc1 = {0.f,0.f,0.f,0.f};
    #pragma unroll
    for (int kit=0;kit<16;kit++){
      int colb = (kit*64 + quad*16) ^ ((lr&7)<<4);
      u32x4 a0 = *(const u32x4*)((char*)hS + lr*1024 + colb);
      u32x4 a1 = *(const u32x4*)((char*)hS + (16+lr)*1024 + colb);
      acc0 = mfma16(a0, bfrag[kit], acc0);
      acc1 = mfma16(a1, bfrag[kit], acc1);
    }
    #pragma unroll
    for (int r=0;r<4;r++){
      gacc[wave][quad*4+r][lr]    = acc0[r];
      gacc[wave][16+quad*4+r][lr] = acc1[r];
    }
    __syncthreads();

    // ---- elementwise LSTM cell for this thread's 2 (b, col) elems ----
    float hv[2];
    #pragma unroll
    for (int j=0;j<2;j++){
      float gi = gacc[0][bb0][cc0+j] + bf2f((u16)(xv[0] >> (16*j)));
      float gf = gacc[1][bb0][cc0+j] + bf2f((u16)(xv[1] >> (16*j)));
      float gg = gacc[2][bb0][cc0+j] + bf2f((u16)(xv[2] >> (16*j)));
      float go = gacc[3][bb0][cc0+j] + bf2f((u16)(xv[3] >> (16*j)));
      float cn = sigm(gf)*cst[j] + sigm(gi)*tanh_ap(gg);
      cst[j] = cn;
      hv[j] = sigm(go)*tanh_ap(cn);
    }
    *(u32*)(feat + (long)(bb0*64 + t)*1024 + cbase + cc0) = pk2(hv[0],hv[1]);

    if (t < 63){
      // publish h slice (1 dword/thread) to coherence point, then post seq flag
      st_cc(hb32 + (t&1)*8192 + bb0*256 + (cbase>>1) + (tid&7), pk2(hv[0],hv[1]));
      asm volatile("s_waitcnt vmcnt(0)" ::: "memory");
      __syncthreads();
      if (tid==0)
        __hip_atomic_store(flags + w, (u32)(t+1), __ATOMIC_RELAXED, __HIP_MEMORY_SCOPE_AGENT);
      // prefetch next step's xp gate inputs; they fly during the barrier wait
      const u16* xp0 = xpb + (long)(bb0*64 + t+1)*2048 + cbase + cc0;
      #pragma unroll
      for (int q=0;q<4;q++) xv[q] = *(const u32*)(xp0 + q*512);
    } else {
      *(float2*)(outH + bb0*512 + cbase + cc0) = make_float2(hv[0], hv[1]);
      *(float2*)(outC + bb0*512 + cbase + cc0) = make_float2(cst[0], cst[1]);
    }
  }
}

// ---------------- Kernel 3: per batch: s=hs@out^T, softmax(e), ctx=attn^T@hs ----------------
__global__ __launch_bounds__(256) void k_attn(const float* __restrict__ hs,
    u16* __restrict__ feat, float* __restrict__ attnOut)
{
  __shared__ u16 stg[16384];      // 32 KB: hsS[64][256] (phase1) then hsT[256][64] (phase3)
  __shared__ float sS[4096];      // 16 KB
  __shared__ u16 aT[4096];        // 8 KB: attn^T [t][e] bf16
  __shared__ float red[8][64];    // 2 KB
  const int tid = threadIdx.x, b = blockIdx.x;
  const int wave = tid>>6, lane = tid&63, quad = lane>>4, lr = lane&15;
  const float* hsb = hs + (long)b*32768;

  // Phase 1: S[e][t] = sum_h hs[e][h]*out[t][h], h in two 256-halves staged to LDS bf16
  f32x4 sacc[4];
  #pragma unroll
  for (int j=0;j<4;j++) sacc[j] = (f32x4){0.f,0.f,0.f,0.f};
  for (int kk=0; kk<2; kk++){
    int row = tid>>2, cc0 = (tid&3)*64;
    #pragma unroll
    for (int c8=0; c8<8; c8++)
      *(u32x4*)(stg + row*256 + cc0 + c8*8) = pk8(hsb + (long)row*512 + kk*256 + cc0 + c8*8);
    __syncthreads();
    for (int kit=0; kit<8; kit++){
      u32x4 af = *(const u32x4*)(stg + (wave*16 + lr)*256 + kit*32 + quad*8);
      #pragma unroll
      for (int j=0;j<4;j++){
        u32x4 bfv = *(const u32x4*)(feat + (long)(b*64 + j*16 + lr)*1024 + kk*256 + kit*32 + quad*8);
        sacc[j] = mfma16(af, bfv, sacc[j]);
      }
    }
    __syncthreads();
  }
  #pragma unroll
  for (int j=0;j<4;j++)
    #pragma unroll
    for (int r=0;r<4;r++)
      sS[(wave*16 + quad*4 + r)*64 + j*16 + lr] = sacc[j][r];
  __syncthreads();

  // Phase 2: softmax over e (rows) per column t; write attn fp32
  {
    int t = tid&63, qtr = tid>>6;
    float m = -1e30f;
    for (int e=qtr*16; e<qtr*16+16; e++) m = fmaxf(m, sS[e*64+t]);
    red[qtr][t] = m;
    __syncthreads();
    m = fmaxf(fmaxf(red[0][t],red[1][t]), fmaxf(red[2][t],red[3][t]));
    float sum = 0.f;
    for (int e=qtr*16; e<qtr*16+16; e++) sum += __expf(sS[e*64+t]-m);
    red[4+qtr][t] = sum;
    __syncthreads();
    float inv = 1.f/(red[4][t]+red[5][t]+red[6][t]+red[7][t]);
    for (int e=qtr*16; e<qtr*16+16; e++){
      float wgt = __expf(sS[e*64+t]-m)*inv;
      aT[t*64+e] = f2bf(wgt);
      attnOut[b*4096 + e*64 + t] = wgt;
    }
  }
  __syncthreads();

  // Phase 3: ctx[t][h] = sum_e attn[e][t]*hs[e][h], via LDS-transposed bf16 hs
  for (int hh=0; hh<2; hh++){
    #pragma unroll
    for (int it=0; it<8; it++){
      int g = tid*8 + it, e = g>>5, hb = g&31;
      const float* p = hsb + (long)e*512 + hh*256 + hb*8;
      f32x4 lo = *(const f32x4*)p, hi = *(const f32x4*)(p+4);
      stg[(hb*8+0)*64 + e] = f2bf(lo[0]);
      stg[(hb*8+1)*64 + e] = f2bf(lo[1]);
      stg[(hb*8+2)*64 + e] = f2bf(lo[2]);
      stg[(hb*8+3)*64 + e] = f2bf(lo[3]);
      stg[(hb*8+4)*64 + e] = f2bf(hi[0]);
      stg[(hb*8+5)*64 + e] = f2bf(hi[1]);
      stg[(hb*8+6)*64 + e] = f2bf(hi[2]);
      stg[(hb*8+7)*64 + e] = f2bf(hi[3]);
    }
    __syncthreads();
    u32x4 a0 = *(const u32x4*)(aT + (wave*16+lr)*64 + quad*8);
    u32x4 a1 = *(const u32x4*)(aT + (wave*16+lr)*64 + 32 + quad*8);
    for (int hn=0; hn<16; hn++){
      f32x4 c = {0.f,0.f,0.f,0.f};
      u32x4 b0 = *(const u32x4*)(stg + (hn*16+lr)*64 + quad*8);
      u32x4 b1 = *(const u32x4*)(stg + (hn*16+lr)*64 + 32 + quad*8);
      c = mfma16(a0, b0, c);
      c = mfma16(a1, b1, c);
      int hcol = hh*256 + hn*16 + lr;
      #pragma unroll
      for (int r=0;r<4;r++){
        int t = wave*16 + quad*4 + r;
        feat[(long)(b*64 + t)*1024 + 512 + hcol] = f2bf(c[r]);
      }
    }
    __syncthreads();
  }
}

// ---------------- Kernel 4: logits = feat @ aff_W^T + aff_b, fp32 out ----------------
__global__ __launch_bounds__(256) void k_logits(const u16* __restrict__ feat,
    const float* __restrict__ affW, const float* __restrict__ affb, float* __restrict__ outL)
{
  __shared__ u16 sm[16384];
  u16* As = sm; u16* Bs = sm + 8192;
  const int tid = threadIdx.x;
  const int m0 = blockIdx.x*128, n0 = blockIdx.y*128;
  const int wave = tid>>6, lane = tid&63, quad = lane>>4, lr = lane&15;
  const int wm = wave>>1, wn = wave&1;
  const int rbase = tid>>3, cb = (tid&7)*8;
  f32x4 acc[4][4];
  #pragma unroll
  for (int i=0;i<4;i++)
    #pragma unroll
    for (int j=0;j<4;j++) acc[i][j] = (f32x4){0.f,0.f,0.f,0.f};

  for (int kb=0; kb<1024; kb+=64){
    #pragma unroll
    for (int i=0;i<4;i++)
      gld16(feat + (long)(m0 + i*32 + rbase)*1024 + kb + cb, As + i*2048 + tid*8);
    #pragma unroll
    for (int i=0;i<4;i++)
      *(u32x4*)(Bs + i*2048 + tid*8) = pk8(affW + (long)(n0 + i*32 + rbase)*1024 + kb + cb);
    __syncthreads();
    #pragma unroll
    for (int k0=0;k0<64;k0+=32){
      u32x4 bf[4];
      #pragma unroll
      for (int j=0;j<4;j++) bf[j] = *(const u32x4*)(Bs + (wn*64 + j*16 + lr)*64 + k0 + quad*8);
      #pragma unroll
      for (int i=0;i<4;i++){
        u32x4 af = *(const u32x4*)(As + (wm*64 + i*16 + lr)*64 + k0 + quad*8);
        #pragma unroll
        for (int j=0;j<4;j++) acc[i][j] = mfma16(af, bf[j], acc[i][j]);
      }
    }
    __syncthreads();
  }
  float bias[4];
  #pragma unroll
  for (int j=0;j<4;j++) bias[j] = affb[n0 + wn*64 + j*16 + lr];
  #pragma unroll
  for (int i=0;i<4;i++)
    #pragma unroll
    for (int j=0;j<4;j++){
      int row = m0 + wm*64 + i*16 + quad*4;
      int col = n0 + wn*64 + j*16 + lr;
      #pragma unroll
      for (int r=0;r<4;r++) outL[(long)(row+r)*32000 + col] = acc[i][j][r] + bias[j];
    }
}

extern "C" void kernel_launch(void* const* d_in, const int* in_sizes, int n_in,
                              void* d_out, int out_size, void* d_ws, size_t ws_size,
                              hipStream_t stream) {
  const int*   xs   = (const int*)d_in[0];
  const float* hs   = (const float*)d_in[1];
  const float* h0   = (const float*)d_in[2];
  const float* c0   = (const float*)d_in[3];
  const float* embW = (const float*)d_in[4];
  const float* Wih  = (const float*)d_in[5];
  const float* Whh  = (const float*)d_in[6];
  const float* bih  = (const float*)d_in[7];
  const float* bhh  = (const float*)d_in[8];
  const float* affW = (const float*)d_in[9];
  const float* affb = (const float*)d_in[10];
  float* out = (float*)d_out;

  char* ws = (char*)d_ws;
  u16* xpb   = (u16*)ws;                             //  8,388,608 B
  u16* feat  = (u16*)(ws + 8388608);                 //  4,194,304 B
  u16* hbuf  = (u16*)(ws + 8388608 + 4194304);       //     65,536 B (2 x [32][512])
  u32* flags = (u32*)(ws + 8388608 + 4194304 + 65536); // 128 B (32 x u32 seq flags)

  float* outHT  = out + 65536000;
  float* outCT  = out + 65552384;
  float* outAtt = out + 65568768;

  k_init<<<64, 256, 0, stream>>>(h0, hbuf + 16384, flags);
  k_xp<<<dim3(16,16), 256, 0, stream>>>(xs, embW, Wih, bih, bhh, xpb);
  k_lstm<<<32, 256, 0, stream>>>(xpb, c0, Whh, feat, hbuf, flags, outHT, outCT);
  k_attn<<<32, 256, 0, stream>>>(hs, feat, outAtt);
  k_logits<<<dim3(16,250), 256, 0, stream>>>(feat, affW, affb, out);
}

// Round 2
// 767.626 us; speedup vs baseline: 1.4604x; 1.1507x over previous
//
#include <hip/hip_runtime.h>

// AttentionDecoder: embed -> LSTM(64 steps) -> dot attention -> vocab projection
// B=32 TD=TE=64 V=32000 D=H=512.
// I/O dtypes: ALL float tensors fp32 (per reference); xs int32. Outputs fp32.
// Internally: convert to bf16 at staging (RNE), MFMA 16x16x32_bf16, fp32 accum.
//
// d_out layout (fp32 elems): logits[32][64][32000] | hT[32][512] | cT[32][512] | attn[32][64][64]
// ws layout: xpb bf16[2048][2048] | feat bf16[2048][1024] | hbuf bf16[2][32][512] | flags u32[32]
//            | affWb bf16[32000][1024]  (only if ws_size permits; 78.2 MB total)

typedef unsigned short u16;
typedef unsigned int u32;
typedef __bf16 bf16x8 __attribute__((ext_vector_type(8)));
typedef float f32x4 __attribute__((ext_vector_type(4)));
typedef u32 u32x4 __attribute__((ext_vector_type(4)));

__device__ __forceinline__ float bf2f(u16 u){ u32 x = ((u32)u)<<16; return __builtin_bit_cast(float, x); }
__device__ __forceinline__ u16 f2bf(float f){ u32 x = __builtin_bit_cast(u32, f); x += 0x7FFFu + ((x>>16)&1u); return (u16)(x>>16); }
__device__ __forceinline__ u32 pk2(float a, float b){ return (u32)f2bf(a) | ((u32)f2bf(b)<<16); }
__device__ __forceinline__ u32x4 pk8(const float* p){
  f32x4 lo = *(const f32x4*)p, hi = *(const f32x4*)(p+4);
  u32x4 r; r[0]=pk2(lo[0],lo[1]); r[1]=pk2(lo[2],lo[3]); r[2]=pk2(hi[0],hi[1]); r[3]=pk2(hi[2],hi[3]);
  return r;
}

__device__ __forceinline__ f32x4 mfma16(u32x4 a, u32x4 b, f32x4 c){
  return __builtin_amdgcn_mfma_f32_16x16x32_bf16(
      __builtin_bit_cast(bf16x8, a), __builtin_bit_cast(bf16x8, b), c, 0, 0, 0);
}

__device__ __forceinline__ void gld16(const void* g, void* l){
  __builtin_amdgcn_global_load_lds(
      (__attribute__((address_space(1))) void*)(void*)g,
      (__attribute__((address_space(3))) void*)l, 16, 0, 0);
}

// Cache-bypass (coherence-point) ops: sc0 sc1 => bypass L1 and per-XCD L2,
// serviced at the die-level coherence point => cross-XCD visible without
// buffer_inv / buffer_wbl2 cache maintenance.
__device__ __forceinline__ void st_cc(u32* p, u32 v){
  asm volatile("global_store_dword %0, %1, off sc0 sc1" :: "v"(p), "v"(v) : "memory");
}
__device__ __forceinline__ u32x4 ld_cc4(const u32* p){
  u32x4 r;
  asm volatile("global_load_dwordx4 %0, %1, off sc0 sc1" : "=v"(r) : "v"(p) : "memory");
  return r;
}

__device__ __forceinline__ float sigm(float x){ x = fminf(fmaxf(x,-30.f),30.f); return 1.f/(1.f+__expf(-x)); }
__device__ __forceinline__ float tanh_ap(float x){ float xc = fminf(fmaxf(x,-15.f),15.f); float e = __expf(-2.f*xc); return (1.f-e)/(1.f+e); }

// ---- init: h0 fp32 -> hbuf[1] bf16; zero the per-WG seq flags ----
__global__ void k_init(const float* __restrict__ h0, u16* __restrict__ hbuf1, u32* __restrict__ flags){
  int i = blockIdx.x*256 + threadIdx.x;
  hbuf1[i] = f2bf(h0[i]);
  if (i < 32) flags[i] = 0u;
}

// ---------------- Kernel 1: xp = embed_W[xs] @ W_ih^T + (b_ih+b_hh), bf16 out ----------------
__global__ __launch_bounds__(256) void k_xp(const int* __restrict__ xs,
    const float* __restrict__ embW, const float* __restrict__ Wih,
    const float* __restrict__ bih, const float* __restrict__ bhh,
    u16* __restrict__ xpb)
{
  __shared__ u16 sm[16384];           // As[128][64] | Bs[128][64] (bf16)
  u16* As = sm; u16* Bs = sm + 8192;
  const int tid = threadIdx.x;
  const int m0 = blockIdx.x*128, n0 = blockIdx.y*128;
  const int wave = tid>>6, lane = tid&63, quad = lane>>4, lr = lane&15;
  const int wm = wave>>1, wn = wave&1;
  const int rbase = tid>>3, cb = (tid&7)*8;   // 8 floats per lane per row-chunk
  int tok[4];
  #pragma unroll
  for (int i=0;i<4;i++) tok[i] = xs[m0 + i*32 + rbase];
  f32x4 acc[4][4];
  #pragma unroll
  for (int i=0;i<4;i++)
    #pragma unroll
    for (int j=0;j<4;j++) acc[i][j] = (f32x4){0.f,0.f,0.f,0.f};

  for (int kb=0; kb<512; kb+=64){
    #pragma unroll
    for (int i=0;i<4;i++)
      *(u32x4*)(As + i*2048 + tid*8) = pk8(embW + (long)tok[i]*512 + kb + cb);
    #pragma unroll
    for (int i=0;i<4;i++)
      *(u32x4*)(Bs + i*2048 + tid*8) = pk8(Wih + (long)(n0 + i*32 + rbase)*512 + kb + cb);
    __syncthreads();
    #pragma unroll
    for (int k0=0;k0<64;k0+=32){
      u32x4 bf[4];
      #pragma unroll
      for (int j=0;j<4;j++) bf[j] = *(const u32x4*)(Bs + (wn*64 + j*16 + lr)*64 + k0 + quad*8);
      #pragma unroll
      for (int i=0;i<4;i++){
        u32x4 af = *(const u32x4*)(As + (wm*64 + i*16 + lr)*64 + k0 + quad*8);
        #pragma unroll
        for (int j=0;j<4;j++) acc[i][j] = mfma16(af, bf[j], acc[i][j]);
      }
    }
    __syncthreads();
  }
  float bias[4];
  #pragma unroll
  for (int j=0;j<4;j++){ int col = n0 + wn*64 + j*16 + lr; bias[j] = bih[col] + bhh[col]; }
  #pragma unroll
  for (int i=0;i<4;i++)
    #pragma unroll
    for (int j=0;j<4;j++){
      int row = m0 + wm*64 + i*16 + quad*4;
      int col = n0 + wn*64 + j*16 + lr;
      #pragma unroll
      for (int r=0;r<4;r++) xpb[(long)(row+r)*2048 + col] = f2bf(acc[i][j][r] + bias[j]);
    }
}

// ---------------- Kernel 2: persistent LSTM, 32 WGs (+ optional affW->bf16 converter WGs) ---
// WG w<32 owns h-cols [w*16, w*16+16); wave q computes gate q; W_hh frags register-resident.
// WGs >=32 (present only when ws has room for affWb) convert aff_W fp32 -> bf16 and exit,
// overlapping the latency-bound LSTM (which leaves 224 CUs idle).
// h exchange: sc0/sc1 cache-bypass stores/loads + per-WG monotonic seq flags. No agent fences.
__global__ __launch_bounds__(256) void k_lstm(const u16* __restrict__ xpb,
    const float* __restrict__ c0, const float* __restrict__ Whh,
    u16* __restrict__ feat, u16* __restrict__ hbuf, u32* __restrict__ flags,
    float* __restrict__ outH, float* __restrict__ outC,
    const float* __restrict__ affW, u16* __restrict__ affWb)
{
  __shared__ u16 hS[16384];           // h staged [32][512] bf16, XOR-swizzled rows
  __shared__ float gacc[4][32][16];   // gate pre-activations
  const int tid = threadIdx.x, w = blockIdx.x;

  if (w >= 32){
    // ---- converter role: affW fp32[32000][1024] -> affWb bf16, grid-stride x8 ----
    const long N = 32768000L;
    long i = ((long)(w - 32)*256 + tid)*8;
    const long stride = (long)(gridDim.x - 32)*256*8;
    for (; i < N; i += stride)
      *(u32x4*)(affWb + i) = pk8(affW + i);
    return;
  }

  const int wave = tid>>6, lane = tid&63, quad = lane>>4, lr = lane&15;
  const int cbase = w*16;

  u32x4 bfrag[16];                    // W_hh B-fragments (fp32 -> bf16 once)
  const float* wrow = Whh + (long)(wave*512 + cbase + lr)*512;
  #pragma unroll
  for (int kit=0;kit<16;kit++) bfrag[kit] = pk8(wrow + kit*32 + quad*8);

  const int bb0 = tid>>3;             // batch row of this thread's 2 h elems
  const int cc0 = (tid*2)&15;         // even col-pair base within the 16-col slice
  float cst[2];
  cst[0] = c0[bb0*512 + cbase + cc0];
  cst[1] = c0[bb0*512 + cbase + cc0 + 1];

  u32* hb32 = (u32*)hbuf;             // [2][32][256] u32 (2 bf16 per u32)

  // xp gate inputs for current step, packed: xv[q] = {col cc0, col cc0+1}
  u32 xv[4];
  {
    const u16* xp0 = xpb + (long)(bb0*64)*2048 + cbase + cc0;
    #pragma unroll
    for (int q=0;q<4;q++) xv[q] = *(const u32*)(xp0 + q*512);
  }

  for (int t=0;t<64;t++){
    // ---- wait for all WGs to have finished step t-1 (per-WG seq flags) ----
    if (t>0){
      if (wave==0){
        for(;;){
          u32 f = __hip_atomic_load(flags + (lane&31), __ATOMIC_RELAXED, __HIP_MEMORY_SCOPE_AGENT);
          if (__all((int)(f >= (u32)t))) break;
        }
      }
      __syncthreads();
    }
    // ---- gather full h[32][512] from coherence point into swizzled LDS ----
    const u32* src = hb32 + ((t+1)&1)*8192;     // t=0 -> buffer 1 (h0, from k_init)
    u32x4 hreg[8];
    #pragma unroll
    for (int k=0;k<8;k++) hreg[k] = ld_cc4(src + k*1024 + tid*4);
    asm volatile("s_waitcnt vmcnt(0)" ::: "memory");
    __builtin_amdgcn_sched_barrier(0);
    #pragma unroll
    for (int k=0;k<8;k++){
      int row  = k*4 + (tid>>6);                // logical h row (batch)
      int colb = (tid&63)*16;                   // byte col within 1KB row
      *(u32x4*)((char*)hS + row*1024 + (colb ^ ((row&7)<<4))) = hreg[k];
    }
    __syncthreads();

    // ---- gates = h @ W_hh^T (this WG's 16 cols x 4 gates) ----
    f32x4 acc0 = {0.f,0.f,0.f,0.f}, acc1 = {0.f,0.f,0.f,0.f};
    #pragma unroll
    for (int kit=0;kit<16;kit++){
      int colb = (kit*64 + quad*16) ^ ((lr&7)<<4);
      u32x4 a0 = *(const u32x4*)((char*)hS + lr*1024 + colb);
      u32x4 a1 = *(const u32x4*)((char*)hS + (16+lr)*1024 + colb);
      acc0 = mfma16(a0, bfrag[kit], acc0);
      acc1 = mfma16(a1, bfrag[kit], acc1);
    }
    #pragma unroll
    for (int r=0;r<4;r++){
      gacc[wave][quad*4+r][lr]    = acc0[r];
      gacc[wave][16+quad*4+r][lr] = acc1[r];
    }
    __syncthreads();

    // ---- elementwise LSTM cell for this thread's 2 (b, col) elems ----
    float hv[2];
    #pragma unroll
    for (int j=0;j<2;j++){
      float gi = gacc[0][bb0][cc0+j] + bf2f((u16)(xv[0] >> (16*j)));
      float gf = gacc[1][bb0][cc0+j] + bf2f((u16)(xv[1] >> (16*j)));
      float gg = gacc[2][bb0][cc0+j] + bf2f((u16)(xv[2] >> (16*j)));
      float go = gacc[3][bb0][cc0+j] + bf2f((u16)(xv[3] >> (16*j)));
      float cn = sigm(gf)*cst[j] + sigm(gi)*tanh_ap(gg);
      cst[j] = cn;
      hv[j] = sigm(go)*tanh_ap(cn);
    }
    *(u32*)(feat + (long)(bb0*64 + t)*1024 + cbase + cc0) = pk2(hv[0],hv[1]);

    if (t < 63){
      // publish h slice (1 dword/thread) to coherence point, then post seq flag
      st_cc(hb32 + (t&1)*8192 + bb0*256 + (cbase>>1) + (tid&7), pk2(hv[0],hv[1]));
      asm volatile("s_waitcnt vmcnt(0)" ::: "memory");
      __syncthreads();
      if (tid==0)
        __hip_atomic_store(flags + w, (u32)(t+1), __ATOMIC_RELAXED, __HIP_MEMORY_SCOPE_AGENT);
      // prefetch next step's xp gate inputs; they fly during the barrier wait
      const u16* xp0 = xpb + (long)(bb0*64 + t+1)*2048 + cbase + cc0;
      #pragma unroll
      for (int q=0;q<4;q++) xv[q] = *(const u32*)(xp0 + q*512);
    } else {
      *(float2*)(outH + bb0*512 + cbase + cc0) = make_float2(hv[0], hv[1]);
      *(float2*)(outC + bb0*512 + cbase + cc0) = make_float2(cst[0], cst[1]);
    }
  }
}

// ---------------- Kernel 3: per batch: s=hs@out^T, softmax(e), ctx=attn^T@hs ----------------
__global__ __launch_bounds__(256) void k_attn(const float* __restrict__ hs,
    u16* __restrict__ feat, float* __restrict__ attnOut)
{
  __shared__ u16 stg[16384];      // 32 KB: hsS[64][256] (phase1) then hsT[256][64] (phase3)
  __shared__ float sS[4096];      // 16 KB
  __shared__ u16 aT[4096];        // 8 KB: attn^T [t][e] bf16
  __shared__ float red[8][64];    // 2 KB
  const int tid = threadIdx.x, b = blockIdx.x;
  const int wave = tid>>6, lane = tid&63, quad = lane>>4, lr = lane&15;
  const float* hsb = hs + (long)b*32768;

  // Phase 1: S[e][t] = sum_h hs[e][h]*out[t][h], h in two 256-halves staged to LDS bf16
  f32x4 sacc[4];
  #pragma unroll
  for (int j=0;j<4;j++) sacc[j] = (f32x4){0.f,0.f,0.f,0.f};
  for (int kk=0; kk<2; kk++){
    int row = tid>>2, cc0 = (tid&3)*64;
    #pragma unroll
    for (int c8=0; c8<8; c8++)
      *(u32x4*)(stg + row*256 + cc0 + c8*8) = pk8(hsb + (long)row*512 + kk*256 + cc0 + c8*8);
    __syncthreads();
    for (int kit=0; kit<8; kit++){
      u32x4 af = *(const u32x4*)(stg + (wave*16 + lr)*256 + kit*32 + quad*8);
      #pragma unroll
      for (int j=0;j<4;j++){
        u32x4 bfv = *(const u32x4*)(feat + (long)(b*64 + j*16 + lr)*1024 + kk*256 + kit*32 + quad*8);
        sacc[j] = mfma16(af, bfv, sacc[j]);
      }
    }
    __syncthreads();
  }
  #pragma unroll
  for (int j=0;j<4;j++)
    #pragma unroll
    for (int r=0;r<4;r++)
      sS[(wave*16 + quad*4 + r)*64 + j*16 + lr] = sacc[j][r];
  __syncthreads();

  // Phase 2: softmax over e (rows) per column t; write attn fp32
  {
    int t = tid&63, qtr = tid>>6;
    float m = -1e30f;
    for (int e=qtr*16; e<qtr*16+16; e++) m = fmaxf(m, sS[e*64+t]);
    red[qtr][t] = m;
    __syncthreads();
    m = fmaxf(fmaxf(red[0][t],red[1][t]), fmaxf(red[2][t],red[3][t]));
    float sum = 0.f;
    for (int e=qtr*16; e<qtr*16+16; e++) sum += __expf(sS[e*64+t]-m);
    red[4+qtr][t] = sum;
    __syncthreads();
    float inv = 1.f/(red[4][t]+red[5][t]+red[6][t]+red[7][t]);
    for (int e=qtr*16; e<qtr*16+16; e++){
      float wgt = __expf(sS[e*64+t]-m)*inv;
      aT[t*64+e] = f2bf(wgt);
      attnOut[b*4096 + e*64 + t] = wgt;
    }
  }
  __syncthreads();

  // Phase 3: ctx[t][h] = sum_e attn[e][t]*hs[e][h], via LDS-transposed bf16 hs
  for (int hh=0; hh<2; hh++){
    #pragma unroll
    for (int it=0; it<8; it++){
      int g = tid*8 + it, e = g>>5, hb = g&31;
      const float* p = hsb + (long)e*512 + hh*256 + hb*8;
      f32x4 lo = *(const f32x4*)p, hi = *(const f32x4*)(p+4);
      stg[(hb*8+0)*64 + e] = f2bf(lo[0]);
      stg[(hb*8+1)*64 + e] = f2bf(lo[1]);
      stg[(hb*8+2)*64 + e] = f2bf(lo[2]);
      stg[(hb*8+3)*64 + e] = f2bf(lo[3]);
      stg[(hb*8+4)*64 + e] = f2bf(hi[0]);
      stg[(hb*8+5)*64 + e] = f2bf(hi[1]);
      stg[(hb*8+6)*64 + e] = f2bf(hi[2]);
      stg[(hb*8+7)*64 + e] = f2bf(hi[3]);
    }
    __syncthreads();
    u32x4 a0 = *(const u32x4*)(aT + (wave*16+lr)*64 + quad*8);
    u32x4 a1 = *(const u32x4*)(aT + (wave*16+lr)*64 + 32 + quad*8);
    for (int hn=0; hn<16; hn++){
      f32x4 c = {0.f,0.f,0.f,0.f};
      u32x4 b0 = *(const u32x4*)(stg + (hn*16+lr)*64 + quad*8);
      u32x4 b1 = *(const u32x4*)(stg + (hn*16+lr)*64 + 32 + quad*8);
      c = mfma16(a0, b0, c);
      c = mfma16(a1, b1, c);
      int hcol = hh*256 + hn*16 + lr;
      #pragma unroll
      for (int r=0;r<4;r++){
        int t = wave*16 + quad*4 + r;
        feat[(long)(b*64 + t)*1024 + 512 + hcol] = f2bf(c[r]);
      }
    }
    __syncthreads();
  }
}

// ---------------- Kernel 4a: logits = feat @ affWb^T + aff_b (bf16 B, gld16 both sides) ----
// 1D grid of 4000 blocks; bijective XCD swizzle (4000 % 8 == 0, 500/XCD) with m fastest,
// so all 16 m-tiles sharing an affW n-panel run on ONE XCD -> panel fetched ~once.
__global__ __launch_bounds__(256) void k_logits_bw(const u16* __restrict__ feat,
    const u16* __restrict__ affWb, const float* __restrict__ affb, float* __restrict__ outL)
{
  __shared__ u16 sm[16384];
  u16* As = sm; u16* Bs = sm + 8192;
  const int tid = threadIdx.x;
  const int flat = blockIdx.x;
  const int logical = (flat & 7)*500 + (flat >> 3);
  const int m0 = (logical & 15)*128, n0 = (logical >> 4)*128;
  const int wave = tid>>6, lane = tid&63, quad = lane>>4, lr = lane&15;
  const int wm = wave>>1, wn = wave&1;
  const int rbase = tid>>3, cb = (tid&7)*8;
  f32x4 acc[4][4];
  #pragma unroll
  for (int i=0;i<4;i++)
    #pragma unroll
    for (int j=0;j<4;j++) acc[i][j] = (f32x4){0.f,0.f,0.f,0.f};

  for (int kb=0; kb<1024; kb+=64){
    #pragma unroll
    for (int i=0;i<4;i++)
      gld16(feat + (long)(m0 + i*32 + rbase)*1024 + kb + cb, As + i*2048 + tid*8);
    #pragma unroll
    for (int i=0;i<4;i++)
      gld16(affWb + (long)(n0 + i*32 + rbase)*1024 + kb + cb, Bs + i*2048 + tid*8);
    __syncthreads();
    #pragma unroll
    for (int k0=0;k0<64;k0+=32){
      u32x4 bf[4];
      #pragma unroll
      for (int j=0;j<4;j++) bf[j] = *(const u32x4*)(Bs + (wn*64 + j*16 + lr)*64 + k0 + quad*8);
      #pragma unroll
      for (int i=0;i<4;i++){
        u32x4 af = *(const u32x4*)(As + (wm*64 + i*16 + lr)*64 + k0 + quad*8);
        #pragma unroll
        for (int j=0;j<4;j++) acc[i][j] = mfma16(af, bf[j], acc[i][j]);
      }
    }
    __syncthreads();
  }
  float bias[4];
  #pragma unroll
  for (int j=0;j<4;j++) bias[j] = affb[n0 + wn*64 + j*16 + lr];
  #pragma unroll
  for (int i=0;i<4;i++)
    #pragma unroll
    for (int j=0;j<4;j++){
      int row = m0 + wm*64 + i*16 + quad*4;
      int col = n0 + wn*64 + j*16 + lr;
      #pragma unroll
      for (int r=0;r<4;r++) outL[(long)(row+r)*32000 + col] = acc[i][j][r] + bias[j];
    }
}

// ---------------- Kernel 4b: fallback (fp32 B, VALU pack) if ws can't hold affWb ----------
__global__ __launch_bounds__(256) void k_logits(const u16* __restrict__ feat,
    const float* __restrict__ affW, const float* __restrict__ affb, float* __restrict__ outL)
{
  __shared__ u16 sm[16384];
  u16* As = sm; u16* Bs = sm + 8192;
  const int tid = threadIdx.x;
  const int m0 = blockIdx.x*128, n0 = blockIdx.y*128;
  const int wave = tid>>6, lane = tid&63, quad = lane>>4, lr = lane&15;
  const int wm = wave>>1, wn = wave&1;
  const int rbase = tid>>3, cb = (tid&7)*8;
  f32x4 acc[4][4];
  #pragma unroll
  for (int i=0;i<4;i++)
    #pragma unroll
    for (int j=0;j<4;j++) acc[i][j] = (f32x4){0.f,0.f,0.f,0.f};

  for (int kb=0; kb<1024; kb+=64){
    #pragma unroll
    for (int i=0;i<4;i++)
      gld16(feat + (long)(m0 + i*32 + rbase)*1024 + kb + cb, As + i*2048 + tid*8);
    #pragma unroll
    for (int i=0;i<4;i++)
      *(u32x4*)(Bs + i*2048 + tid*8) = pk8(affW + (long)(n0 + i*32 + rbase)*1024 + kb + cb);
    __syncthreads();
    #pragma unroll
    for (int k0=0;k0<64;k0+=32){
      u32x4 bf[4];
      #pragma unroll
      for (int j=0;j<4;j++) bf[j] = *(const u32x4*)(Bs + (wn*64 + j*16 + lr)*64 + k0 + quad*8);
      #pragma unroll
      for (int i=0;i<4;i++){
        u32x4 af = *(const u32x4*)(As + (wm*64 + i*16 + lr)*64 + k0 + quad*8);
        #pragma unroll
        for (int j=0;j<4;j++) acc[i][j] = mfma16(af, bf[j], acc[i][j]);
      }
    }
    __syncthreads();
  }
  float bias[4];
  #pragma unroll
  for (int j=0;j<4;j++) bias[j] = affb[n0 + wn*64 + j*16 + lr];
  #pragma unroll
  for (int i=0;i<4;i++)
    #pragma unroll
    for (int j=0;j<4;j++){
      int row = m0 + wm*64 + i*16 + quad*4;
      int col = n0 + wn*64 + j*16 + lr;
      #pragma unroll
      for (int r=0;r<4;r++) outL[(long)(row+r)*32000 + col] = acc[i][j][r] + bias[j];
    }
}

extern "C" void kernel_launch(void* const* d_in, const int* in_sizes, int n_in,
                              void* d_out, int out_size, void* d_ws, size_t ws_size,
                              hipStream_t stream) {
  const int*   xs   = (const int*)d_in[0];
  const float* hs   = (const float*)d_in[1];
  const float* h0   = (const float*)d_in[2];
  const float* c0   = (const float*)d_in[3];
  const float* embW = (const float*)d_in[4];
  const float* Wih  = (const float*)d_in[5];
  const float* Whh  = (const float*)d_in[6];
  const float* bih  = (const float*)d_in[7];
  const float* bhh  = (const float*)d_in[8];
  const float* affW = (const float*)d_in[9];
  const float* affb = (const float*)d_in[10];
  float* out = (float*)d_out;

  char* ws = (char*)d_ws;
  u16* xpb   = (u16*)ws;                               //  8,388,608 B
  u16* feat  = (u16*)(ws + 8388608);                   //  4,194,304 B
  u16* hbuf  = (u16*)(ws + 8388608 + 4194304);         //     65,536 B (2 x [32][512])
  u32* flags = (u32*)(ws + 8388608 + 4194304 + 65536); //        128 B (32 x u32 seq flags)
  u16* affWb = (u16*)(ws + 12648576);                  // 65,536,000 B (bf16 aff_W)
  const bool useBf = ws_size >= (size_t)(12648576) + 65536000;

  float* outHT  = out + 65536000;
  float* outCT  = out + 65552384;
  float* outAtt = out + 65568768;

  k_init<<<64, 256, 0, stream>>>(h0, hbuf + 16384, flags);
  k_xp<<<dim3(16,16), 256, 0, stream>>>(xs, embW, Wih, bih, bhh, xpb);
  k_lstm<<<useBf ? 256 : 32, 256, 0, stream>>>(xpb, c0, Whh, feat, hbuf, flags, outHT, outCT, affW, affWb);
  k_attn<<<32, 256, 0, stream>>>(hs, feat, outAtt);
  if (useBf)
    k_logits_bw<<<4000, 256, 0, stream>>>(feat, affWb, affb, out);
  else
    k_logits<<<dim3(16,250), 256, 0, stream>>>(feat, affW, affb, out);
}

// Round 3
// 763.592 us; speedup vs baseline: 1.4681x; 1.0053x over previous
//
#include <hip/hip_runtime.h>

// AttentionDecoder: embed -> LSTM(64 steps) -> dot attention -> vocab projection
// B=32 TD=TE=64 V=32000 D=H=512.
// I/O dtypes: ALL float tensors fp32 (per reference); xs int32. Outputs fp32.
// Internally: convert to bf16 at staging (RNE), MFMA 16x16x32_bf16, fp32 accum.
//
// d_out layout (fp32 elems): logits[32][64][32000] | hT[32][512] | cT[32][512] | attn[32][64][64]
// ws layout: xpb bf16[2048][2048] | feat bf16[2048][1024] | pairbuf u32[2][16384][2]
//            | affWb bf16[32000][1024]  (only if ws_size permits; 78.4 MB total)
//
// LSTM h-exchange: ONE 8-byte {data,tag} packet per thread per step at the coherence
// point (sc0 sc1). Consumers poll the data itself until tag==t -> data already in regs.
// No fences, no flag array, no store-ack wait, no end-of-step barrier.

typedef unsigned short u16;
typedef unsigned int u32;
typedef __bf16 bf16x8 __attribute__((ext_vector_type(8)));
typedef float f32x4 __attribute__((ext_vector_type(4)));
typedef u32 u32x2 __attribute__((ext_vector_type(2)));
typedef u32 u32x4 __attribute__((ext_vector_type(4)));

__device__ __forceinline__ float bf2f(u16 u){ u32 x = ((u32)u)<<16; return __builtin_bit_cast(float, x); }
__device__ __forceinline__ u16 f2bf(float f){ u32 x = __builtin_bit_cast(u32, f); x += 0x7FFFu + ((x>>16)&1u); return (u16)(x>>16); }
__device__ __forceinline__ u32 pk2(float a, float b){ return (u32)f2bf(a) | ((u32)f2bf(b)<<16); }
__device__ __forceinline__ u32x4 pk8(const float* p){
  f32x4 lo = *(const f32x4*)p, hi = *(const f32x4*)(p+4);
  u32x4 r; r[0]=pk2(lo[0],lo[1]); r[1]=pk2(lo[2],lo[3]); r[2]=pk2(hi[0],hi[1]); r[3]=pk2(hi[2],hi[3]);
  return r;
}

__device__ __forceinline__ f32x4 mfma16(u32x4 a, u32x4 b, f32x4 c){
  return __builtin_amdgcn_mfma_f32_16x16x32_bf16(
      __builtin_bit_cast(bf16x8, a), __builtin_bit_cast(bf16x8, b), c, 0, 0, 0);
}

__device__ __forceinline__ void gld16(const void* g, void* l){
  __builtin_amdgcn_global_load_lds(
      (__attribute__((address_space(1))) void*)(void*)g,
      (__attribute__((address_space(3))) void*)l, 16, 0, 0);
}

// Cache-bypass (coherence-point) ops: sc0 sc1 => bypass L1 and per-XCD L2,
// serviced at the die-level coherence point => cross-XCD visible without
// buffer_inv / buffer_wbl2 cache maintenance.
__device__ __forceinline__ void st_cc2(u32* p, u32x2 v){
  asm volatile("global_store_dwordx2 %0, %1, off sc0 sc1" :: "v"(p), "v"(v) : "memory");
}
__device__ __forceinline__ u32x4 ld_cc4(const u32* p){
  u32x4 r;
  asm volatile("global_load_dwordx4 %0, %1, off sc0 sc1" : "=v"(r) : "v"(p) : "memory");
  return r;
}

__device__ __forceinline__ float sigm(float x){ x = fminf(fmaxf(x,-30.f),30.f); return 1.f/(1.f+__expf(-x)); }
__device__ __forceinline__ float tanh_ap(float x){ float xc = fminf(fmaxf(x,-15.f),15.f); float e = __expf(-2.f*xc); return (1.f-e)/(1.f+e); }

// ---- init: pairbuf buf1 = {h0 bf16 pairs, tag 0}; buf0 tags = invalid ----
__global__ void k_init(const float* __restrict__ h0, u32* __restrict__ pb){
  int i = blockIdx.x*256 + threadIdx.x;              // 0..16383, one pair each
  u32 d = pk2(h0[2*i], h0[2*i+1]);
  *(u32x2*)(pb + 32768 + i*2) = (u32x2){d, 0u};      // buf1: h0, tag 0 (= step -1)
  *(u32x2*)(pb + i*2)         = (u32x2){0u, 0xFFFFFFFFu}; // buf0: never-matching tag
}

// ---------------- Kernel 1: xp = embed_W[xs] @ W_ih^T + (b_ih+b_hh), bf16 out ----------------
__global__ __launch_bounds__(256) void k_xp(const int* __restrict__ xs,
    const float* __restrict__ embW, const float* __restrict__ Wih,
    const float* __restrict__ bih, const float* __restrict__ bhh,
    u16* __restrict__ xpb)
{
  __shared__ u16 sm[16384];           // As[128][64] | Bs[128][64] (bf16)
  u16* As = sm; u16* Bs = sm + 8192;
  const int tid = threadIdx.x;
  const int m0 = blockIdx.x*128, n0 = blockIdx.y*128;
  const int wave = tid>>6, lane = tid&63, quad = lane>>4, lr = lane&15;
  const int wm = wave>>1, wn = wave&1;
  const int rbase = tid>>3, cb = (tid&7)*8;   // 8 floats per lane per row-chunk
  int tok[4];
  #pragma unroll
  for (int i=0;i<4;i++) tok[i] = xs[m0 + i*32 + rbase];
  f32x4 acc[4][4];
  #pragma unroll
  for (int i=0;i<4;i++)
    #pragma unroll
    for (int j=0;j<4;j++) acc[i][j] = (f32x4){0.f,0.f,0.f,0.f};

  for (int kb=0; kb<512; kb+=64){
    #pragma unroll
    for (int i=0;i<4;i++)
      *(u32x4*)(As + i*2048 + tid*8) = pk8(embW + (long)tok[i]*512 + kb + cb);
    #pragma unroll
    for (int i=0;i<4;i++)
      *(u32x4*)(Bs + i*2048 + tid*8) = pk8(Wih + (long)(n0 + i*32 + rbase)*512 + kb + cb);
    __syncthreads();
    #pragma unroll
    for (int k0=0;k0<64;k0+=32){
      u32x4 bf[4];
      #pragma unroll
      for (int j=0;j<4;j++) bf[j] = *(const u32x4*)(Bs + (wn*64 + j*16 + lr)*64 + k0 + quad*8);
      #pragma unroll
      for (int i=0;i<4;i++){
        u32x4 af = *(const u32x4*)(As + (wm*64 + i*16 + lr)*64 + k0 + quad*8);
        #pragma unroll
        for (int j=0;j<4;j++) acc[i][j] = mfma16(af, bf[j], acc[i][j]);
      }
    }
    __syncthreads();
  }
  float bias[4];
  #pragma unroll
  for (int j=0;j<4;j++){ int col = n0 + wn*64 + j*16 + lr; bias[j] = bih[col] + bhh[col]; }
  #pragma unroll
  for (int i=0;i<4;i++)
    #pragma unroll
    for (int j=0;j<4;j++){
      int row = m0 + wm*64 + i*16 + quad*4;
      int col = n0 + wn*64 + j*16 + lr;
      #pragma unroll
      for (int r=0;r<4;r++) xpb[(long)(row+r)*2048 + col] = f2bf(acc[i][j][r] + bias[j]);
    }
}

// ---------------- Kernel 2: persistent LSTM, 32 WGs (+ optional affW->bf16 converter WGs) ---
// WG w<32 owns h-cols [w*16, w*16+16); wave q computes gate q; W_hh frags register-resident.
// WGs >=32 convert aff_W fp32 -> bf16 and exit (overlaps latency-bound LSTM).
// Sync: {data,tag} 8B packets; consumers poll data until tag==t. Safety: each WG's
// step-t stores are issued only after two __syncthreads that follow its collective
// poll of ALL step-(t-1) packets => every WG's reads of the buffer being overwritten
// are complete (seeing a WG's packet implies it passed its pre-store barriers).
__global__ __launch_bounds__(256) void k_lstm(const u16* __restrict__ xpb,
    const float* __restrict__ c0, const float* __restrict__ Whh,
    u16* __restrict__ feat, u32* __restrict__ pb,
    float* __restrict__ outH, float* __restrict__ outC,
    const float* __restrict__ affW, u16* __restrict__ affWb)
{
  __shared__ u16 hS[16384];           // h staged [32][512] bf16, XOR-swizzled rows
  __shared__ float gacc[4][32][16];   // gate pre-activations
  const int tid = threadIdx.x, w = blockIdx.x;

  if (w >= 32){
    // ---- converter role: affW fp32[32000][1024] -> affWb bf16, grid-stride ----
    const long N = 32768000L;
    long i = ((long)(w - 32)*256 + tid)*8;
    const long stride = (long)(gridDim.x - 32)*256*8;
    for (; i < N; i += stride)
      *(u32x4*)(affWb + i) = pk8(affW + i);
    return;
  }

  const int wave = tid>>6, lane = tid&63, quad = lane>>4, lr = lane&15;
  const int cbase = w*16;

  u32x4 bfrag[16];                    // W_hh B-fragments (fp32 -> bf16 once)
  const float* wrow = Whh + (long)(wave*512 + cbase + lr)*512;
  #pragma unroll
  for (int kit=0;kit<16;kit++) bfrag[kit] = pk8(wrow + kit*32 + quad*8);

  const int bb0 = tid>>3;             // batch row of this thread's 2 h elems
  const int cc0 = (tid*2)&15;         // even col-pair base within the 16-col slice
  float cst[2];
  cst[0] = c0[bb0*512 + cbase + cc0];
  cst[1] = c0[bb0*512 + cbase + cc0 + 1];

  // this thread's pair slot (u32 pair index) within a buffer
  u32* mySlot = pb /*+ buf*32768*/ + (bb0*256 + (cbase>>1) + (tid&7))*2;

  // xp gate inputs for current step, packed: xv[q] = {col cc0, col cc0+1}
  u32 xv[4];
  {
    const u16* xp0 = xpb + (long)(bb0*64)*2048 + cbase + cc0;
    #pragma unroll
    for (int q=0;q<4;q++) xv[q] = *(const u32*)(xp0 + q*512);
  }

  for (int t=0;t<64;t++){
    // ---- poll step t-1 packets: loads ARE the data gather ----
    const u32 want = (u32)t;
    const char* srcB = (const char*)pb + ((t+1)&1)*131072;   // t=0 -> buf1 (h0)
    u32x4 pr[16];
    for(;;){
      #pragma unroll
      for (int k=0;k<8;k++){
        const char* a = srcB + k*8192 + tid*32;
        pr[2*k]   = ld_cc4((const u32*)a);
        pr[2*k+1] = ld_cc4((const u32*)(a+16));
      }
      asm volatile("s_waitcnt vmcnt(0)" ::: "memory");
      u32 bad = 0;
      #pragma unroll
      for (int k=0;k<16;k++) bad |= (pr[k][1]^want) | (pr[k][3]^want);
      if (!__any((int)bad)) break;
    }
    __builtin_amdgcn_sched_barrier(0);
    #pragma unroll
    for (int k=0;k<8;k++){
      u32x4 d = (u32x4){pr[2*k][0], pr[2*k][2], pr[2*k+1][0], pr[2*k+1][2]};
      int row  = k*4 + (tid>>6);                // logical h row (batch)
      int colb = (tid&63)*16;                   // byte col within 1KB row
      *(u32x4*)((char*)hS + row*1024 + (colb ^ ((row&7)<<4))) = d;
    }
    __syncthreads();

    // ---- gates = h @ W_hh^T (this WG's 16 cols x 4 gates) ----
    f32x4 acc0 = {0.f,0.f,0.f,0.f}, acc1 = {0.f,0.f,0.f,0.f};
    #pragma unroll
    for (int kit=0;kit<16;kit++){
      int colb = (kit*64 + quad*16) ^ ((lr&7)<<4);
      u32x4 a0 = *(const u32x4*)((char*)hS + lr*1024 + colb);
      u32x4 a1 = *(const u32x4*)((char*)hS + (16+lr)*1024 + colb);
      acc0 = mfma16(a0, bfrag[kit], acc0);
      acc1 = mfma16(a1, bfrag[kit], acc1);
    }
    #pragma unroll
    for (int r=0;r<4;r++){
      gacc[wave][quad*4+r][lr]    = acc0[r];
      gacc[wave][16+quad*4+r][lr] = acc1[r];
    }
    __syncthreads();

    // ---- elementwise LSTM cell for this thread's 2 (b, col) elems ----
    float hv[2];
    #pragma unroll
    for (int j=0;j<2;j++){
      float gi = gacc[0][bb0][cc0+j] + bf2f((u16)(xv[0] >> (16*j)));
      float gf = gacc[1][bb0][cc0+j] + bf2f((u16)(xv[1] >> (16*j)));
      float gg = gacc[2][bb0][cc0+j] + bf2f((u16)(xv[2] >> (16*j)));
      float go = gacc[3][bb0][cc0+j] + bf2f((u16)(xv[3] >> (16*j)));
      float cn = sigm(gf)*cst[j] + sigm(gi)*tanh_ap(gg);
      cst[j] = cn;
      hv[j] = sigm(go)*tanh_ap(cn);
    }
    u32 hp = pk2(hv[0],hv[1]);

    if (t < 63){
      // single 8B {data, tag=t+1} packet: fire and forget (critical path first)
      st_cc2((u32*)((char*)mySlot + (t&1)*131072), (u32x2){hp, (u32)(t+1)});
      *(u32*)(feat + (long)(bb0*64 + t)*1024 + cbase + cc0) = hp;
      // prefetch next step's xp gate inputs; they fly during the next poll
      const u16* xp0 = xpb + (long)(bb0*64 + t+1)*2048 + cbase + cc0;
      #pragma unroll
      for (int q=0;q<4;q++) xv[q] = *(const u32*)(xp0 + q*512);
    } else {
      *(u32*)(feat + (long)(bb0*64 + t)*1024 + cbase + cc0) = hp;
      *(float2*)(outH + bb0*512 + cbase + cc0) = make_float2(hv[0], hv[1]);
      *(float2*)(outC + bb0*512 + cbase + cc0) = make_float2(cst[0], cst[1]);
    }
  }
}

// ---------------- Kernel 3: per batch: s=hs@out^T, softmax(e), ctx=attn^T@hs ----------------
__global__ __launch_bounds__(256) void k_attn(const float* __restrict__ hs,
    u16* __restrict__ feat, float* __restrict__ attnOut)
{
  __shared__ u16 stg[16384];      // 32 KB: hsS[64][256] (phase1) then hsT[256][64] (phase3)
  __shared__ float sS[4096];      // 16 KB
  __shared__ u16 aT[4096];        // 8 KB: attn^T [t][e] bf16
  __shared__ float red[8][64];    // 2 KB
  const int tid = threadIdx.x, b = blockIdx.x;
  const int wave = tid>>6, lane = tid&63, quad = lane>>4, lr = lane&15;
  const float* hsb = hs + (long)b*32768;

  // Phase 1: S[e][t] = sum_h hs[e][h]*out[t][h], h in two 256-halves staged to LDS bf16
  f32x4 sacc[4];
  #pragma unroll
  for (int j=0;j<4;j++) sacc[j] = (f32x4){0.f,0.f,0.f,0.f};
  for (int kk=0; kk<2; kk++){
    int row = tid>>2, cc0 = (tid&3)*64;
    #pragma unroll
    for (int c8=0; c8<8; c8++)
      *(u32x4*)(stg + row*256 + cc0 + c8*8) = pk8(hsb + (long)row*512 + kk*256 + cc0 + c8*8);
    __syncthreads();
    for (int kit=0; kit<8; kit++){
      u32x4 af = *(const u32x4*)(stg + (wave*16 + lr)*256 + kit*32 + quad*8);
      #pragma unroll
      for (int j=0;j<4;j++){
        u32x4 bfv = *(const u32x4*)(feat + (long)(b*64 + j*16 + lr)*1024 + kk*256 + kit*32 + quad*8);
        sacc[j] = mfma16(af, bfv, sacc[j]);
      }
    }
    __syncthreads();
  }
  #pragma unroll
  for (int j=0;j<4;j++)
    #pragma unroll
    for (int r=0;r<4;r++)
      sS[(wave*16 + quad*4 + r)*64 + j*16 + lr] = sacc[j][r];
  __syncthreads();

  // Phase 2: softmax over e (rows) per column t; write attn fp32
  {
    int t = tid&63, qtr = tid>>6;
    float m = -1e30f;
    for (int e=qtr*16; e<qtr*16+16; e++) m = fmaxf(m, sS[e*64+t]);
    red[qtr][t] = m;
    __syncthreads();
    m = fmaxf(fmaxf(red[0][t],red[1][t]), fmaxf(red[2][t],red[3][t]));
    float sum = 0.f;
    for (int e=qtr*16; e<qtr*16+16; e++) sum += __expf(sS[e*64+t]-m);
    red[4+qtr][t] = sum;
    __syncthreads();
    float inv = 1.f/(red[4][t]+red[5][t]+red[6][t]+red[7][t]);
    for (int e=qtr*16; e<qtr*16+16; e++){
      float wgt = __expf(sS[e*64+t]-m)*inv;
      aT[t*64+e] = f2bf(wgt);
      attnOut[b*4096 + e*64 + t] = wgt;
    }
  }
  __syncthreads();

  // Phase 3: ctx[t][h] = sum_e attn[e][t]*hs[e][h], via LDS-transposed bf16 hs
  for (int hh=0; hh<2; hh++){
    #pragma unroll
    for (int it=0; it<8; it++){
      int g = tid*8 + it, e = g>>5, hb = g&31;
      const float* p = hsb + (long)e*512 + hh*256 + hb*8;
      f32x4 lo = *(const f32x4*)p, hi = *(const f32x4*)(p+4);
      stg[(hb*8+0)*64 + e] = f2bf(lo[0]);
      stg[(hb*8+1)*64 + e] = f2bf(lo[1]);
      stg[(hb*8+2)*64 + e] = f2bf(lo[2]);
      stg[(hb*8+3)*64 + e] = f2bf(lo[3]);
      stg[(hb*8+4)*64 + e] = f2bf(hi[0]);
      stg[(hb*8+5)*64 + e] = f2bf(hi[1]);
      stg[(hb*8+6)*64 + e] = f2bf(hi[2]);
      stg[(hb*8+7)*64 + e] = f2bf(hi[3]);
    }
    __syncthreads();
    u32x4 a0 = *(const u32x4*)(aT + (wave*16+lr)*64 + quad*8);
    u32x4 a1 = *(const u32x4*)(aT + (wave*16+lr)*64 + 32 + quad*8);
    for (int hn=0; hn<16; hn++){
      f32x4 c = {0.f,0.f,0.f,0.f};
      u32x4 b0 = *(const u32x4*)(stg + (hn*16+lr)*64 + quad*8);
      u32x4 b1 = *(const u32x4*)(stg + (hn*16+lr)*64 + 32 + quad*8);
      c = mfma16(a0, b0, c);
      c = mfma16(a1, b1, c);
      int hcol = hh*256 + hn*16 + lr;
      #pragma unroll
      for (int r=0;r<4;r++){
        int t = wave*16 + quad*4 + r;
        feat[(long)(b*64 + t)*1024 + 512 + hcol] = f2bf(c[r]);
      }
    }
    __syncthreads();
  }
}

// ---------------- Kernel 4a: logits = feat @ affWb^T + aff_b (bf16 B, gld16 both sides) ----
// 1D grid of 4000 blocks; bijective XCD swizzle (4000 % 8 == 0, 500/XCD) with m fastest,
// so all 16 m-tiles sharing an affW n-panel run on ONE XCD -> panel fetched ~once.
__global__ __launch_bounds__(256) void k_logits_bw(const u16* __restrict__ feat,
    const u16* __restrict__ affWb, const float* __restrict__ affb, float* __restrict__ outL)
{
  __shared__ u16 sm[16384];
  u16* As = sm; u16* Bs = sm + 8192;
  const int tid = threadIdx.x;
  const int flat = blockIdx.x;
  const int logical = (flat & 7)*500 + (flat >> 3);
  const int m0 = (logical & 15)*128, n0 = (logical >> 4)*128;
  const int wave = tid>>6, lane = tid&63, quad = lane>>4, lr = lane&15;
  const int wm = wave>>1, wn = wave&1;
  const int rbase = tid>>3, cb = (tid&7)*8;
  f32x4 acc[4][4];
  #pragma unroll
  for (int i=0;i<4;i++)
    #pragma unroll
    for (int j=0;j<4;j++) acc[i][j] = (f32x4){0.f,0.f,0.f,0.f};

  for (int kb=0; kb<1024; kb+=64){
    #pragma unroll
    for (int i=0;i<4;i++)
      gld16(feat + (long)(m0 + i*32 + rbase)*1024 + kb + cb, As + i*2048 + tid*8);
    #pragma unroll
    for (int i=0;i<4;i++)
      gld16(affWb + (long)(n0 + i*32 + rbase)*1024 + kb + cb, Bs + i*2048 + tid*8);
    __syncthreads();
    #pragma unroll
    for (int k0=0;k0<64;k0+=32){
      u32x4 bf[4];
      #pragma unroll
      for (int j=0;j<4;j++) bf[j] = *(const u32x4*)(Bs + (wn*64 + j*16 + lr)*64 + k0 + quad*8);
      #pragma unroll
      for (int i=0;i<4;i++){
        u32x4 af = *(const u32x4*)(As + (wm*64 + i*16 + lr)*64 + k0 + quad*8);
        #pragma unroll
        for (int j=0;j<4;j++) acc[i][j] = mfma16(af, bf[j], acc[i][j]);
      }
    }
    __syncthreads();
  }
  float bias[4];
  #pragma unroll
  for (int j=0;j<4;j++) bias[j] = affb[n0 + wn*64 + j*16 + lr];
  #pragma unroll
  for (int i=0;i<4;i++)
    #pragma unroll
    for (int j=0;j<4;j++){
      int row = m0 + wm*64 + i*16 + quad*4;
      int col = n0 + wn*64 + j*16 + lr;
      #pragma unroll
      for (int r=0;r<4;r++) outL[(long)(row+r)*32000 + col] = acc[i][j][r] + bias[j];
    }
}

// ---------------- Kernel 4b: fallback (fp32 B, VALU pack) if ws can't hold affWb ----------
__global__ __launch_bounds__(256) void k_logits(const u16* __restrict__ feat,
    const float* __restrict__ affW, const float* __restrict__ affb, float* __restrict__ outL)
{
  __shared__ u16 sm[16384];
  u16* As = sm; u16* Bs = sm + 8192;
  const int tid = threadIdx.x;
  const int m0 = blockIdx.x*128, n0 = blockIdx.y*128;
  const int wave = tid>>6, lane = tid&63, quad = lane>>4, lr = lane&15;
  const int wm = wave>>1, wn = wave&1;
  const int rbase = tid>>3, cb = (tid&7)*8;
  f32x4 acc[4][4];
  #pragma unroll
  for (int i=0;i<4;i++)
    #pragma unroll
    for (int j=0;j<4;j++) acc[i][j] = (f32x4){0.f,0.f,0.f,0.f};

  for (int kb=0; kb<1024; kb+=64){
    #pragma unroll
    for (int i=0;i<4;i++)
      gld16(feat + (long)(m0 + i*32 + rbase)*1024 + kb + cb, As + i*2048 + tid*8);
    #pragma unroll
    for (int i=0;i<4;i++)
      *(u32x4*)(Bs + i*2048 + tid*8) = pk8(affW + (long)(n0 + i*32 + rbase)*1024 + kb + cb);
    __syncthreads();
    #pragma unroll
    for (int k0=0;k0<64;k0+=32){
      u32x4 bf[4];
      #pragma unroll
      for (int j=0;j<4;j++) bf[j] = *(const u32x4*)(Bs + (wn*64 + j*16 + lr)*64 + k0 + quad*8);
      #pragma unroll
      for (int i=0;i<4;i++){
        u32x4 af = *(const u32x4*)(As + (wm*64 + i*16 + lr)*64 + k0 + quad*8);
        #pragma unroll
        for (int j=0;j<4;j++) acc[i][j] = mfma16(af, bf[j], acc[i][j]);
      }
    }
    __syncthreads();
  }
  float bias[4];
  #pragma unroll
  for (int j=0;j<4;j++) bias[j] = affb[n0 + wn*64 + j*16 + lr];
  #pragma unroll
  for (int i=0;i<4;i++)
    #pragma unroll
    for (int j=0;j<4;j++){
      int row = m0 + wm*64 + i*16 + quad*4;
      int col = n0 + wn*64 + j*16 + lr;
      #pragma unroll
      for (int r=0;r<4;r++) outL[(long)(row+r)*32000 + col] = acc[i][j][r] + bias[j];
    }
}

extern "C" void kernel_launch(void* const* d_in, const int* in_sizes, int n_in,
                              void* d_out, int out_size, void* d_ws, size_t ws_size,
                              hipStream_t stream) {
  const int*   xs   = (const int*)d_in[0];
  const float* hs   = (const float*)d_in[1];
  const float* h0   = (const float*)d_in[2];
  const float* c0   = (const float*)d_in[3];
  const float* embW = (const float*)d_in[4];
  const float* Wih  = (const float*)d_in[5];
  const float* Whh  = (const float*)d_in[6];
  const float* bih  = (const float*)d_in[7];
  const float* bhh  = (const float*)d_in[8];
  const float* affW = (const float*)d_in[9];
  const float* affb = (const float*)d_in[10];
  float* out = (float*)d_out;

  char* ws = (char*)d_ws;
  u16* xpb   = (u16*)ws;                               //  8,388,608 B
  u16* feat  = (u16*)(ws + 8388608);                   //  4,194,304 B
  u32* pb    = (u32*)(ws + 12582912);                  //    262,144 B (2 x 16384 x {data,tag})
  u16* affWb = (u16*)(ws + 12845056);                  // 65,536,000 B (bf16 aff_W)
  const bool useBf = ws_size >= (size_t)12845056 + 65536000;

  float* outHT  = out + 65536000;
  float* outCT  = out + 65552384;
  float* outAtt = out + 65568768;

  k_init<<<64, 256, 0, stream>>>(h0, pb);
  k_xp<<<dim3(16,16), 256, 0, stream>>>(xs, embW, Wih, bih, bhh, xpb);
  k_lstm<<<useBf ? 256 : 32, 256, 0, stream>>>(xpb, c0, Whh, feat, pb, outHT, outCT, affW, affWb);
  k_attn<<<32, 256, 0, stream>>>(hs, feat, outAtt);
  if (useBf)
    k_logits_bw<<<4000, 256, 0, stream>>>(feat, affWb, affb, out);
  else
    k_logits<<<dim3(16,250), 256, 0, stream>>>(feat, affW, affb, out);
}